// Round 1
// baseline (300.286 us; speedup 1.0000x reference)
//
#include <hip/hip_runtime.h>

#define V3 (128 * 128 * 128)   // 2097152 voxels per volume

// ---------------- block reduction (wave64) ----------------
__device__ __forceinline__ float block_reduce(float v, float* sm) {
#pragma unroll
  for (int off = 32; off > 0; off >>= 1) v += __shfl_down(v, off, 64);
  int lane = threadIdx.x & 63;
  int wid  = threadIdx.x >> 6;
  if (lane == 0) sm[wid] = v;
  __syncthreads();
  float r = 0.f;
  if ((int)threadIdx.x < (int)(blockDim.x >> 6)) r = sm[threadIdx.x];
  if (wid == 0) {
#pragma unroll
    for (int off = 4; off > 0; off >>= 1) r += __shfl_down(r, off, 64);
  }
  __syncthreads();
  return r;  // valid on thread 0
}

// ---------------- pred_mask area sums (per t) ----------------
__global__ __launch_bounds__(256) void area_kernel(const float* __restrict__ pm,
                                                   float* __restrict__ acc) {
  __shared__ float sm[8];
  const int t = blockIdx.y;
  const float* p = pm + (size_t)t * V3;
  float s = 0.f;
  for (int i = blockIdx.x * blockDim.x + threadIdx.x; i < V3;
       i += gridDim.x * blockDim.x)
    s += p[i];
  s = block_reduce(s, sm);
  if (threadIdx.x == 0) atomicAdd(acc + t, s);
}

// ---------------- flow gradient (squared forward diffs) ----------------
__global__ __launch_bounds__(256) void grad_kernel(const float* __restrict__ fl,
                                                   float* __restrict__ acc) {
  __shared__ float sm[8];
  const int n = 9 * V3;
  float s = 0.f;
  for (int i = blockIdx.x * blockDim.x + threadIdx.x; i < n;
       i += gridDim.x * blockDim.x) {
    int rem = i & (V3 - 1);
    int d = rem >> 14;
    int h = (rem >> 7) & 127;
    int w = rem & 127;
    float f = fl[i];
    if (d < 127) { float x = fl[i + 16384] - f; s += x * x; }
    if (h < 127) { float x = fl[i + 128]   - f; s += x * x; }
    if (w < 127) { float x = fl[i + 1]     - f; s += x * x; }
  }
  s = block_reduce(s, sm);
  if (threadIdx.x == 0) atomicAdd(acc, s);
}

// ---------------- NCC pass 1: W-window + H-window box sums ----------------
// grid (4 h-tiles, 128 d), block 128 threads (one per w).
// Writes 5 fields: I_sum, I2_sum, J_sum, J2_sum, IJ_sum (each 128^3 f32).
__global__ __launch_bounds__(128) void n1_kernel(const float* __restrict__ I0,
                                                 const float* __restrict__ J,
                                                 float* __restrict__ F) {
  __shared__ float ldsI[128];
  __shared__ float ldsJ[128];
  __shared__ float ring[9][5][128];
  const int w  = threadIdx.x;
  const int d  = blockIdx.y;
  const int h0 = blockIdx.x * 32;
  const float* Ib = I0 + (size_t)d * 16384;
  const float* Jb = J  + (size_t)d * 16384;

  auto fill = [&](int hh) {
    int slot = (hh + 36) % 9;
    __syncthreads();  // prior consumers of lds rows / this ring slot done
    bool valid = (hh >= 0) && (hh < 128);
    if (valid) {
      ldsI[w] = Ib[hh * 128 + w];
      ldsJ[w] = Jb[hh * 128 + w];
    }
    __syncthreads();
    float sI = 0.f, sI2 = 0.f, sJ = 0.f, sJ2 = 0.f, sIJ = 0.f;
    if (valid) {
#pragma unroll
      for (int k = -4; k <= 4; ++k) {
        int ww = w + k;
        if (ww >= 0 && ww < 128) {
          float a = ldsI[ww], b = ldsJ[ww];
          sI += a; sI2 += a * a; sJ += b; sJ2 += b * b; sIJ += a * b;
        }
      }
    }
    ring[slot][0][w] = sI;
    ring[slot][1][w] = sI2;
    ring[slot][2][w] = sJ;
    ring[slot][3][w] = sJ2;
    ring[slot][4][w] = sIJ;
  };

  for (int hh = h0 - 4; hh < h0 + 4; ++hh) fill(hh);

  for (int h = h0; h < h0 + 32; ++h) {
    fill(h + 4);
    __syncthreads();
    float o0 = 0.f, o1 = 0.f, o2 = 0.f, o3 = 0.f, o4 = 0.f;
#pragma unroll
    for (int s = 0; s < 9; ++s) {
      o0 += ring[s][0][w];
      o1 += ring[s][1][w];
      o2 += ring[s][2][w];
      o3 += ring[s][3][w];
      o4 += ring[s][4][w];
    }
    size_t base = (size_t)d * 16384 + (size_t)h * 128 + w;
    F[base]            = o0;
    F[V3 + base]       = o1;
    F[2 * (size_t)V3 + base] = o2;
    F[3 * (size_t)V3 + base] = o3;
    F[4 * (size_t)V3 + base] = o4;
  }
}

// ---------------- NCC pass 2: D-window sum + cc + reduce ----------------
// grid (64 h-pairs, 4 d-tiles), block 256 threads (2 h rows x 128 w).
__global__ __launch_bounds__(256) void n2_kernel(const float* __restrict__ F,
                                                 float* __restrict__ acc) {
  __shared__ float sm[8];
  const int w  = threadIdx.x & 127;
  const int h  = blockIdx.x * 2 + (threadIdx.x >> 7);
  const int d0 = blockIdx.y * 32;
  const int hw = h * 128 + w;

  float rI[9], rI2[9], rJ[9], rJ2[9], rIJ[9];
#pragma unroll
  for (int k = 0; k < 9; ++k) {
    int dd = d0 - 4 + k;
    bool v = (dd >= 0) && (dd < 128);
    size_t base = (size_t)(v ? dd : 0) * 16384 + hw;
    rI[k]  = v ? F[base] : 0.f;
    rI2[k] = v ? F[(size_t)V3 + base] : 0.f;
    rJ[k]  = v ? F[2 * (size_t)V3 + base] : 0.f;
    rJ2[k] = v ? F[3 * (size_t)V3 + base] : 0.f;
    rIJ[k] = v ? F[4 * (size_t)V3 + base] : 0.f;
  }

  const float inv_win = 1.0f / 729.0f;
  float accv = 0.f;
  for (int d = d0; d < d0 + 32; ++d) {
    float Is = 0.f, I2s = 0.f, Js = 0.f, J2s = 0.f, IJs = 0.f;
#pragma unroll
    for (int k = 0; k < 9; ++k) {
      Is += rI[k]; I2s += rI2[k]; Js += rJ[k]; J2s += rJ2[k]; IJs += rIJ[k];
    }
    float cross = IJs - Is * Js * inv_win;
    float Ivar  = I2s - Is * Is * inv_win;
    float Jvar  = J2s - Js * Js * inv_win;
    float cc = cross * cross / (Ivar * Jvar + 1e-5f);
    accv += cc;
    // shift window (static indices only)
#pragma unroll
    for (int k = 0; k < 8; ++k) {
      rI[k] = rI[k + 1]; rI2[k] = rI2[k + 1]; rJ[k] = rJ[k + 1];
      rJ2[k] = rJ2[k + 1]; rIJ[k] = rIJ[k + 1];
    }
    int dd = d + 5;
    bool v = dd < 128;
    size_t base = (size_t)(v ? dd : 0) * 16384 + hw;
    rI[8]  = v ? F[base] : 0.f;
    rI2[8] = v ? F[(size_t)V3 + base] : 0.f;
    rJ[8]  = v ? F[2 * (size_t)V3 + base] : 0.f;
    rJ2[8] = v ? F[3 * (size_t)V3 + base] : 0.f;
    rIJ[8] = v ? F[4 * (size_t)V3 + base] : 0.f;
  }

  accv = block_reduce(accv, sm);
  if (threadIdx.x == 0) atomicAdd(acc, accv);
}

// ---------------- final scalar combine ----------------
__global__ void final_kernel(const float* __restrict__ ws,
                             const float* __restrict__ td,
                             float* __restrict__ out) {
  if (threadIdx.x != 0 || blockIdx.x != 0) return;
  float area[4];
  float amax = -1e30f;
#pragma unroll
  for (int t = 0; t < 4; ++t) {
    area[t] = ws[t];
    amax = fmaxf(amax, area[t]);
  }
  float a[4];
#pragma unroll
  for (int t = 0; t < 4; ++t) a[t] = area[t] / amax;

  float sc = 0.f;
  int cnt = 0;
  for (int i = 0; i < 2; ++i)
    for (int j = i + 1; j < 3; ++j)
      for (int k = j + 1; k < 4; ++k) {
        float lam = (td[j] - td[i] + 1e-5f) / (td[k] - td[i] + 1e-5f);
        float e = a[j] - a[i] - lam * (a[k] - a[i]);
        sc += e * e;
        ++cnt;
      }
  sc /= (float)cnt;

  float ncc  = 1.0f - ws[7] / (3.0f * (float)V3);
  float grad = ws[4] / (3.0f * 9.0f * 127.0f * 128.0f * 128.0f);
  out[0] = ncc + 0.1f * grad + 0.1f * sc;
}

extern "C" void kernel_launch(void* const* d_in, const int* in_sizes, int n_in,
                              void* d_out, int out_size, void* d_ws, size_t ws_size,
                              hipStream_t stream) {
  const float* image      = (const float*)d_in[0];
  // d_in[1] = mask (unused by the reference loss)
  const float* pred_image = (const float*)d_in[2];
  const float* pred_mask  = (const float*)d_in[3];
  const float* flow       = (const float*)d_in[4];
  const float* time_diff  = (const float*)d_in[5];
  float* out = (float*)d_out;
  float* wsf = (float*)d_ws;
  float* F   = wsf + 64;  // 5 * V3 floats of field scratch after scalar slots

  // zero scalar accumulators: [0..3] area, [4] grad sum, [7] cc sum
  hipMemsetAsync(d_ws, 0, 256, stream);

  hipLaunchKernelGGL(area_kernel, dim3(512, 4), dim3(256), 0, stream,
                     pred_mask, wsf);
  hipLaunchKernelGGL(grad_kernel, dim3(2048), dim3(256), 0, stream,
                     flow, wsf + 4);

  for (int t = 0; t < 3; ++t) {
    const float* J = pred_image + (size_t)(t + 1) * V3;
    hipLaunchKernelGGL(n1_kernel, dim3(4, 128), dim3(128), 0, stream,
                       image, J, F);
    hipLaunchKernelGGL(n2_kernel, dim3(64, 4), dim3(256), 0, stream,
                       F, wsf + 7);
  }

  hipLaunchKernelGGL(final_kernel, dim3(1), dim3(1), 0, stream,
                     wsf, time_diff, out);
}

// Round 2
// 217.406 us; speedup vs baseline: 1.3812x; 1.3812x over previous
//
#include <hip/hip_runtime.h>

#define V3 (128 * 128 * 128)   // 2097152 voxels per volume

// ---------------- block reduction (wave64) ----------------
__device__ __forceinline__ float block_reduce(float v, float* sm) {
#pragma unroll
  for (int off = 32; off > 0; off >>= 1) v += __shfl_down(v, off, 64);
  int lane = threadIdx.x & 63;
  int wid  = threadIdx.x >> 6;
  if (lane == 0) sm[wid] = v;
  __syncthreads();
  float r = 0.f;
  if ((int)threadIdx.x < (int)(blockDim.x >> 6)) r = sm[threadIdx.x];
  if (wid == 0) {
#pragma unroll
    for (int off = 4; off > 0; off >>= 1) r += __shfl_down(r, off, 64);
  }
  __syncthreads();
  return r;  // valid on thread 0
}

// ---------------- pred_mask area sums (per t), float4 ----------------
__global__ __launch_bounds__(256) void area_kernel(const float* __restrict__ pm,
                                                   float* __restrict__ acc) {
  __shared__ float sm[8];
  const int t = blockIdx.y;
  const float* p = pm + (size_t)t * V3;
  const int n4 = V3 / 4;
  float s = 0.f;
  for (int i = blockIdx.x * blockDim.x + threadIdx.x; i < n4;
       i += gridDim.x * blockDim.x) {
    float4 a = *(const float4*)(p + 4 * (size_t)i);
    s += (a.x + a.y) + (a.z + a.w);
  }
  s = block_reduce(s, sm);
  if (threadIdx.x == 0) atomicAdd(acc + t, s);
}

// ---------------- flow gradient (squared forward diffs), float4 ----------------
__global__ __launch_bounds__(256) void grad_kernel(const float* __restrict__ fl,
                                                   float* __restrict__ acc) {
  __shared__ float sm[8];
  const int n4 = 9 * V3 / 4;
  float s = 0.f;
  for (int i4 = blockIdx.x * blockDim.x + threadIdx.x; i4 < n4;
       i4 += gridDim.x * blockDim.x) {
    int i = i4 * 4;
    int rem = i & (V3 - 1);
    int d = rem >> 14;
    int h = (rem >> 7) & 127;
    int w = rem & 127;  // multiple of 4
    float4 a = *(const float4*)(fl + i);
    float x;
    x = a.y - a.x; s += x * x;
    x = a.z - a.y; s += x * x;
    x = a.w - a.z; s += x * x;
    if (w < 124) { float b = fl[i + 4]; x = b - a.w; s += x * x; }
    if (h < 127) {
      float4 bh = *(const float4*)(fl + i + 128);
      x = bh.x - a.x; s += x * x; x = bh.y - a.y; s += x * x;
      x = bh.z - a.z; s += x * x; x = bh.w - a.w; s += x * x;
    }
    if (d < 127) {
      float4 bd = *(const float4*)(fl + i + 16384);
      x = bd.x - a.x; s += x * x; x = bd.y - a.y; s += x * x;
      x = bd.z - a.z; s += x * x; x = bd.w - a.w; s += x * x;
    }
  }
  s = block_reduce(s, sm);
  if (threadIdx.x == 0) atomicAdd(acc, s);
}

// ---------------- NCC pass 1: W-window + H-window box sums ----------------
// Block = 256 threads = 2 d-slices x 128 w. Grid = (8 h-chunks, 64 d-pairs).
// Each block walks 16+8 rows of h with a running H-sum; per-thread LDS ring
// (thread-private -> no sync); double-buffered row staging (1 sync/row).
// WITH_I=true additionally computes & writes the I_sum / I2_sum planes.
template <bool WITH_I>
__global__ __launch_bounds__(256) void n1_kernel(const float* __restrict__ I0,
                                                 const float* __restrict__ J,
                                                 float* __restrict__ FI,
                                                 float* __restrict__ FJ) {
  constexpr int NF = WITH_I ? 5 : 3;
  __shared__ float sI[2][2][136];
  __shared__ float sJ[2][2][136];
  __shared__ float ring[2][9][NF][128];
  __shared__ float* dummy;  // silence unused warnings pattern (no-op)
  (void)dummy;

  const int w  = threadIdx.x & 127;
  const int dl = threadIdx.x >> 7;
  const int d  = blockIdx.y * 2 + dl;
  const int h0 = blockIdx.x * 16;
  const float* Ib = I0 + (size_t)d * 16384;
  const float* Jb = J  + (size_t)d * 16384;

  // zero this thread's ring slots (thread-private, no sync needed)
#pragma unroll
  for (int sl = 0; sl < 9; ++sl)
#pragma unroll
    for (int f = 0; f < NF; ++f) ring[dl][sl][f][w] = 0.f;

  float S[NF];
#pragma unroll
  for (int f = 0; f < NF; ++f) S[f] = 0.f;

  for (int hh = h0 - 4; hh < h0 + 20; ++hh) {
    const int buf = hh & 1;
    const bool valid = (hh >= 0) && (hh < 128);
    if (valid) {
      sI[dl][buf][4 + w] = Ib[hh * 128 + w];
      sJ[dl][buf][4 + w] = Jb[hh * 128 + w];
      if (w < 4)    { sI[dl][buf][w] = 0.f;     sJ[dl][buf][w] = 0.f; }
      if (w >= 124) { sI[dl][buf][w + 8] = 0.f; sJ[dl][buf][w + 8] = 0.f; }
    }
    __syncthreads();

    float Wn[NF];
#pragma unroll
    for (int f = 0; f < NF; ++f) Wn[f] = 0.f;
    if (valid) {
#pragma unroll
      for (int k = 0; k < 9; ++k) {
        float a = sI[dl][buf][w + k];
        float b = sJ[dl][buf][w + k];
        if (WITH_I) {
          Wn[0] += a; Wn[1] += a * a;
          Wn[2] += b; Wn[3] += b * b; Wn[4] += a * b;
        } else {
          Wn[0] += b; Wn[1] += b * b; Wn[2] += a * b;
        }
      }
    }

    const int slot = (hh + 36) % 9;
#pragma unroll
    for (int f = 0; f < NF; ++f) {
      float old = ring[dl][slot][f][w];
      ring[dl][slot][f][w] = Wn[f];
      S[f] += Wn[f] - old;
    }

    const int ho = hh - 4;
    if (ho >= h0) {  // ho < h0+16 guaranteed by loop bound
      size_t base = (size_t)d * 16384 + (size_t)ho * 128 + w;
      if (WITH_I) {
        FI[base]                 = S[0];
        FI[(size_t)V3 + base]    = S[1];
        FJ[base]                 = S[2];
        FJ[(size_t)V3 + base]    = S[3];
        FJ[2 * (size_t)V3 + base] = S[4];
      } else {
        FJ[base]                 = S[0];
        FJ[(size_t)V3 + base]    = S[1];
        FJ[2 * (size_t)V3 + base] = S[2];
      }
    }
  }
}

// ---------------- NCC pass 2: running D-window + cc + reduce ----------------
// Block = 256 threads = 2 h-rows x 128 w. Grid = (64 h-pairs, 8 d-chunks of 16).
// Running D-sum with add(d+5)/sub(d-4) reloads (planes are L3-resident).
__global__ __launch_bounds__(256) void n2_kernel(const float* __restrict__ FI,
                                                 const float* __restrict__ FJ,
                                                 float* __restrict__ acc) {
  __shared__ float sm[8];
  const int w  = threadIdx.x & 127;
  const int h  = blockIdx.x * 2 + (threadIdx.x >> 7);
  const int d0 = blockIdx.y * 16;
  const int hw = h * 128 + w;

  const float* P0 = FI;
  const float* P1 = FI + (size_t)V3;
  const float* P2 = FJ;
  const float* P3 = FJ + (size_t)V3;
  const float* P4 = FJ + 2 * (size_t)V3;

  float S0 = 0.f, S1 = 0.f, S2 = 0.f, S3 = 0.f, S4 = 0.f;
#pragma unroll
  for (int k = 0; k < 9; ++k) {
    int dd = d0 - 4 + k;
    bool v = (dd >= 0) && (dd < 128);
    size_t a = (size_t)(v ? dd : 0) * 16384 + hw;
    S0 += v ? P0[a] : 0.f;
    S1 += v ? P1[a] : 0.f;
    S2 += v ? P2[a] : 0.f;
    S3 += v ? P3[a] : 0.f;
    S4 += v ? P4[a] : 0.f;
  }

  const float inv_win = 1.0f / 729.0f;
  float accv = 0.f;
  for (int d = d0; d < d0 + 16; ++d) {
    float cross = S4 - S0 * S2 * inv_win;
    float Ivar  = S1 - S0 * S0 * inv_win;
    float Jvar  = S3 - S2 * S2 * inv_win;
    accv += cross * cross / (Ivar * Jvar + 1e-5f);

    int da = d + 5, ds = d - 4;
    bool va = da < 128, vs = ds >= 0;
    size_t aa = (size_t)(va ? da : 0) * 16384 + hw;
    size_t as = (size_t)(vs ? ds : 0) * 16384 + hw;
    S0 += (va ? P0[aa] : 0.f) - (vs ? P0[as] : 0.f);
    S1 += (va ? P1[aa] : 0.f) - (vs ? P1[as] : 0.f);
    S2 += (va ? P2[aa] : 0.f) - (vs ? P2[as] : 0.f);
    S3 += (va ? P3[aa] : 0.f) - (vs ? P3[as] : 0.f);
    S4 += (va ? P4[aa] : 0.f) - (vs ? P4[as] : 0.f);
  }

  accv = block_reduce(accv, sm);
  if (threadIdx.x == 0) atomicAdd(acc, accv);
}

// ---------------- final scalar combine ----------------
__global__ void final_kernel(const float* __restrict__ ws,
                             const float* __restrict__ td,
                             float* __restrict__ out) {
  if (threadIdx.x != 0 || blockIdx.x != 0) return;
  float area[4];
  float amax = -1e30f;
#pragma unroll
  for (int t = 0; t < 4; ++t) {
    area[t] = ws[t];
    amax = fmaxf(amax, area[t]);
  }
  float a[4];
#pragma unroll
  for (int t = 0; t < 4; ++t) a[t] = area[t] / amax;

  float sc = 0.f;
  int cnt = 0;
  for (int i = 0; i < 2; ++i)
    for (int j = i + 1; j < 3; ++j)
      for (int k = j + 1; k < 4; ++k) {
        float lam = (td[j] - td[i] + 1e-5f) / (td[k] - td[i] + 1e-5f);
        float e = a[j] - a[i] - lam * (a[k] - a[i]);
        sc += e * e;
        ++cnt;
      }
  sc /= (float)cnt;

  float ncc  = 1.0f - ws[7] / (3.0f * (float)V3);
  float grad = ws[4] / (3.0f * 9.0f * 127.0f * 128.0f * 128.0f);
  out[0] = ncc + 0.1f * grad + 0.1f * sc;
}

extern "C" void kernel_launch(void* const* d_in, const int* in_sizes, int n_in,
                              void* d_out, int out_size, void* d_ws, size_t ws_size,
                              hipStream_t stream) {
  const float* image      = (const float*)d_in[0];
  // d_in[1] = mask (unused by the reference loss)
  const float* pred_image = (const float*)d_in[2];
  const float* pred_mask  = (const float*)d_in[3];
  const float* flow       = (const float*)d_in[4];
  const float* time_diff  = (const float*)d_in[5];
  float* out = (float*)d_out;
  float* wsf = (float*)d_ws;
  float* FI  = wsf + 64;                 // 2 planes (I_sum, I2_sum)
  float* FJ  = FI + 2 * (size_t)V3;      // 3 planes (J_sum, J2_sum, IJ_sum)

  // zero scalar accumulators: [0..3] area, [4] grad sum, [7] cc sum
  hipMemsetAsync(d_ws, 0, 256, stream);

  hipLaunchKernelGGL(area_kernel, dim3(512, 4), dim3(256), 0, stream,
                     pred_mask, wsf);
  hipLaunchKernelGGL(grad_kernel, dim3(4608), dim3(256), 0, stream,
                     flow, wsf + 4);

  for (int t = 0; t < 3; ++t) {
    const float* J = pred_image + (size_t)(t + 1) * V3;
    if (t == 0) {
      hipLaunchKernelGGL((n1_kernel<true>), dim3(8, 64), dim3(256), 0, stream,
                         image, J, FI, FJ);
    } else {
      hipLaunchKernelGGL((n1_kernel<false>), dim3(8, 64), dim3(256), 0, stream,
                         image, J, FI, FJ);
    }
    hipLaunchKernelGGL(n2_kernel, dim3(64, 8), dim3(256), 0, stream,
                       FI, FJ, wsf + 7);
  }

  hipLaunchKernelGGL(final_kernel, dim3(1), dim3(1), 0, stream,
                     wsf, time_diff, out);
}

// Round 3
// 153.988 us; speedup vs baseline: 1.9501x; 1.4118x over previous
//
#include <hip/hip_runtime.h>

#define V3 (128 * 128 * 128)   // 2097152 voxels per volume

// ---------------- block reduction (wave64) ----------------
__device__ __forceinline__ float block_reduce(float v, float* sm) {
#pragma unroll
  for (int off = 32; off > 0; off >>= 1) v += __shfl_down(v, off, 64);
  int lane = threadIdx.x & 63;
  int wid  = threadIdx.x >> 6;
  if (lane == 0) sm[wid] = v;
  __syncthreads();
  float r = 0.f;
  if ((int)threadIdx.x < (int)(blockDim.x >> 6)) r = sm[threadIdx.x];
  if (wid == 0) {
#pragma unroll
    for (int off = 4; off > 0; off >>= 1) r += __shfl_down(r, off, 64);
  }
  __syncthreads();
  return r;  // valid on thread 0
}

// ---------------- pred_mask area sums (per t), float4 ----------------
__global__ __launch_bounds__(256) void area_kernel(const float* __restrict__ pm,
                                                   float* __restrict__ acc) {
  __shared__ float sm[8];
  const int t = blockIdx.y;
  const float* p = pm + (size_t)t * V3;
  const int n4 = V3 / 4;
  float s = 0.f;
  for (int i = blockIdx.x * blockDim.x + threadIdx.x; i < n4;
       i += gridDim.x * blockDim.x) {
    float4 a = *(const float4*)(p + 4 * (size_t)i);
    s += (a.x + a.y) + (a.z + a.w);
  }
  s = block_reduce(s, sm);
  if (threadIdx.x == 0) atomicAdd(acc + t, s);
}

// ---------------- flow gradient: register d-walk, 2 loads/iter ----------------
// grid (16 h-tiles, 8 d-tiles, 9 c), block 256 = 8 h-rows x 32 w4.
__global__ __launch_bounds__(256) void grad_kernel(const float* __restrict__ fl,
                                                   float* __restrict__ acc) {
  __shared__ float sm[8];
  const int w4 = threadIdx.x & 31;
  const int hl = threadIdx.x >> 5;           // 0..7
  const int h  = blockIdx.x * 8 + hl;        // 0..127
  const int d0 = blockIdx.y * 16;
  const int c  = blockIdx.z;                 // 0..8
  const float* p = fl + (size_t)c * V3 + (size_t)h * 128 + w4 * 4;
  const bool hv = (h < 127);

  float s = 0.f;
  float4 cur  = *(const float4*)(p + (size_t)d0 * 16384);
  float4 curh = hv ? *(const float4*)(p + (size_t)d0 * 16384 + 128) : cur;

#pragma unroll
  for (int dd = 0; dd < 16; ++dd) {
    const int d = d0 + dd;
    const bool dv = (d < 127);
    float4 nxt = cur, nxth = curh;
    if (dv) {
      nxt = *(const float4*)(p + (size_t)(d + 1) * 16384);
      if (hv) nxth = *(const float4*)(p + (size_t)(d + 1) * 16384 + 128);
    }
    float x;
    x = cur.y - cur.x; s += x * x;
    x = cur.z - cur.y; s += x * x;
    x = cur.w - cur.z; s += x * x;
    float nx = __shfl_down(cur.x, 1, 64);
    if (w4 != 31) { x = nx - cur.w; s += x * x; }
    if (hv) {
      x = curh.x - cur.x; s += x * x;
      x = curh.y - cur.y; s += x * x;
      x = curh.z - cur.z; s += x * x;
      x = curh.w - cur.w; s += x * x;
    }
    if (dv) {
      x = nxt.x - cur.x; s += x * x;
      x = nxt.y - cur.y; s += x * x;
      x = nxt.z - cur.z; s += x * x;
      x = nxt.w - cur.w; s += x * x;
    }
    cur = nxt; curh = nxth;
  }
  s = block_reduce(s, sm);
  if (threadIdx.x == 0) atomicAdd(acc, s);
}

// ---------------- NCC pass 1: W-window + H-window box sums ----------------
// Block = 256 threads = 2 d-slices x 128 w. Grid = (8 h-chunks, 64 d-pairs, NT).
// blockIdx.z selects the J frame / FJ plane-triple.
template <bool WITH_I>
__global__ __launch_bounds__(256) void n1_kernel(const float* __restrict__ I0,
                                                 const float* __restrict__ Jall,
                                                 float* __restrict__ FI,
                                                 float* __restrict__ FJall) {
  constexpr int NF = WITH_I ? 5 : 3;
  __shared__ float sI[2][2][136];
  __shared__ float sJ[2][2][136];
  __shared__ float ring[2][9][NF][128];

  const int tz = blockIdx.z;
  const float* J = Jall + (size_t)tz * V3;
  float* FJ = FJall + (size_t)tz * 3 * (size_t)V3;

  const int w  = threadIdx.x & 127;
  const int dl = threadIdx.x >> 7;
  const int d  = blockIdx.y * 2 + dl;
  const int h0 = blockIdx.x * 16;
  const float* Ib = I0 + (size_t)d * 16384;
  const float* Jb = J  + (size_t)d * 16384;

#pragma unroll
  for (int sl = 0; sl < 9; ++sl)
#pragma unroll
    for (int f = 0; f < NF; ++f) ring[dl][sl][f][w] = 0.f;

  float S[NF];
#pragma unroll
  for (int f = 0; f < NF; ++f) S[f] = 0.f;

  for (int hh = h0 - 4; hh < h0 + 20; ++hh) {
    const int buf = hh & 1;
    const bool valid = (hh >= 0) && (hh < 128);
    if (valid) {
      sI[dl][buf][4 + w] = Ib[hh * 128 + w];
      sJ[dl][buf][4 + w] = Jb[hh * 128 + w];
      if (w < 4)    { sI[dl][buf][w] = 0.f;     sJ[dl][buf][w] = 0.f; }
      if (w >= 124) { sI[dl][buf][w + 8] = 0.f; sJ[dl][buf][w + 8] = 0.f; }
    }
    __syncthreads();

    float Wn[NF];
#pragma unroll
    for (int f = 0; f < NF; ++f) Wn[f] = 0.f;
    if (valid) {
#pragma unroll
      for (int k = 0; k < 9; ++k) {
        float a = sI[dl][buf][w + k];
        float b = sJ[dl][buf][w + k];
        if (WITH_I) {
          Wn[0] += a; Wn[1] += a * a;
          Wn[2] += b; Wn[3] += b * b; Wn[4] += a * b;
        } else {
          Wn[0] += b; Wn[1] += b * b; Wn[2] += a * b;
        }
      }
    }

    const int slot = (hh + 36) % 9;
#pragma unroll
    for (int f = 0; f < NF; ++f) {
      float old = ring[dl][slot][f][w];
      ring[dl][slot][f][w] = Wn[f];
      S[f] += Wn[f] - old;
    }

    const int ho = hh - 4;
    if (ho >= h0) {
      size_t base = (size_t)d * 16384 + (size_t)ho * 128 + w;
      if (WITH_I) {
        FI[base]                  = S[0];
        FI[(size_t)V3 + base]     = S[1];
        FJ[base]                  = S[2];
        FJ[(size_t)V3 + base]     = S[3];
        FJ[2 * (size_t)V3 + base] = S[4];
      } else {
        FJ[base]                  = S[0];
        FJ[(size_t)V3 + base]     = S[1];
        FJ[2 * (size_t)V3 + base] = S[2];
      }
    }
  }
}

// ---------------- NCC pass 2: running D-window + cc + reduce ----------------
// Block = 256 = 2 h-rows x 128 w. Grid = (64 h-pairs, 8 d-chunks, NT).
__global__ __launch_bounds__(256) void n2_kernel(const float* __restrict__ FI,
                                                 const float* __restrict__ FJall,
                                                 float* __restrict__ acc) {
  __shared__ float sm[8];
  const float* FJ = FJall + (size_t)blockIdx.z * 3 * (size_t)V3;
  const int w  = threadIdx.x & 127;
  const int h  = blockIdx.x * 2 + (threadIdx.x >> 7);
  const int d0 = blockIdx.y * 16;
  const int hw = h * 128 + w;

  const float* P0 = FI;
  const float* P1 = FI + (size_t)V3;
  const float* P2 = FJ;
  const float* P3 = FJ + (size_t)V3;
  const float* P4 = FJ + 2 * (size_t)V3;

  float S0 = 0.f, S1 = 0.f, S2 = 0.f, S3 = 0.f, S4 = 0.f;
#pragma unroll
  for (int k = 0; k < 9; ++k) {
    int dd = d0 - 4 + k;
    bool v = (dd >= 0) && (dd < 128);
    size_t a = (size_t)(v ? dd : 0) * 16384 + hw;
    S0 += v ? P0[a] : 0.f;
    S1 += v ? P1[a] : 0.f;
    S2 += v ? P2[a] : 0.f;
    S3 += v ? P3[a] : 0.f;
    S4 += v ? P4[a] : 0.f;
  }

  const float inv_win = 1.0f / 729.0f;
  float accv = 0.f;
#pragma unroll 4
  for (int d = d0; d < d0 + 16; ++d) {
    float cross = S4 - S0 * S2 * inv_win;
    float Ivar  = S1 - S0 * S0 * inv_win;
    float Jvar  = S3 - S2 * S2 * inv_win;
    accv += cross * cross / (Ivar * Jvar + 1e-5f);

    int da = d + 5, ds = d - 4;
    bool va = da < 128, vs = ds >= 0;
    size_t aa = (size_t)(va ? da : 0) * 16384 + hw;
    size_t as = (size_t)(vs ? ds : 0) * 16384 + hw;
    S0 += (va ? P0[aa] : 0.f) - (vs ? P0[as] : 0.f);
    S1 += (va ? P1[aa] : 0.f) - (vs ? P1[as] : 0.f);
    S2 += (va ? P2[aa] : 0.f) - (vs ? P2[as] : 0.f);
    S3 += (va ? P3[aa] : 0.f) - (vs ? P3[as] : 0.f);
    S4 += (va ? P4[aa] : 0.f) - (vs ? P4[as] : 0.f);
  }

  accv = block_reduce(accv, sm);
  if (threadIdx.x == 0) atomicAdd(acc, accv);
}

// ---------------- final scalar combine ----------------
__global__ void final_kernel(const float* __restrict__ ws,
                             const float* __restrict__ td,
                             float* __restrict__ out) {
  if (threadIdx.x != 0 || blockIdx.x != 0) return;
  float area[4];
  float amax = -1e30f;
#pragma unroll
  for (int t = 0; t < 4; ++t) {
    area[t] = ws[t];
    amax = fmaxf(amax, area[t]);
  }
  float a[4];
#pragma unroll
  for (int t = 0; t < 4; ++t) a[t] = area[t] / amax;

  float sc = 0.f;
  int cnt = 0;
  for (int i = 0; i < 2; ++i)
    for (int j = i + 1; j < 3; ++j)
      for (int k = j + 1; k < 4; ++k) {
        float lam = (td[j] - td[i] + 1e-5f) / (td[k] - td[i] + 1e-5f);
        float e = a[j] - a[i] - lam * (a[k] - a[i]);
        sc += e * e;
        ++cnt;
      }
  sc /= (float)cnt;

  float ncc  = 1.0f - ws[7] / (3.0f * (float)V3);
  float grad = ws[4] / (3.0f * 9.0f * 127.0f * 128.0f * 128.0f);
  out[0] = ncc + 0.1f * grad + 0.1f * sc;
}

extern "C" void kernel_launch(void* const* d_in, const int* in_sizes, int n_in,
                              void* d_out, int out_size, void* d_ws, size_t ws_size,
                              hipStream_t stream) {
  const float* image      = (const float*)d_in[0];
  // d_in[1] = mask (unused by the reference loss)
  const float* pred_image = (const float*)d_in[2];
  const float* pred_mask  = (const float*)d_in[3];
  const float* flow       = (const float*)d_in[4];
  const float* time_diff  = (const float*)d_in[5];
  float* out = (float*)d_out;
  float* wsf = (float*)d_ws;
  float* FI  = wsf + 64;                 // 2 planes (I_sum, I2_sum)
  float* FJ  = FI + 2 * (size_t)V3;      // J plane-triples

  // zero scalar accumulators: [0..3] area, [4] grad sum, [7] cc sum
  hipMemsetAsync(d_ws, 0, 256, stream);

  hipLaunchKernelGGL(area_kernel, dim3(512, 4), dim3(256), 0, stream,
                     pred_mask, wsf);
  hipLaunchKernelGGL(grad_kernel, dim3(16, 8, 9), dim3(256), 0, stream,
                     flow, wsf + 4);

  const size_t need_fused = (64 + 11 * (size_t)V3) * sizeof(float);
  if (ws_size >= need_fused) {
    // fused path: FJ holds 3 t-triples (9 planes) concurrently
    hipLaunchKernelGGL((n1_kernel<true>), dim3(8, 64, 1), dim3(256), 0, stream,
                       image, pred_image + (size_t)V3, FI, FJ);
    hipLaunchKernelGGL((n1_kernel<false>), dim3(8, 64, 2), dim3(256), 0, stream,
                       image, pred_image + 2 * (size_t)V3, FI,
                       FJ + 3 * (size_t)V3);
    hipLaunchKernelGGL(n2_kernel, dim3(64, 8, 3), dim3(256), 0, stream,
                       FI, FJ, wsf + 7);
  } else {
    // sequential path: one J triple reused across t (5 planes total)
    for (int t = 0; t < 3; ++t) {
      const float* J = pred_image + (size_t)(t + 1) * V3;
      if (t == 0) {
        hipLaunchKernelGGL((n1_kernel<true>), dim3(8, 64, 1), dim3(256), 0,
                           stream, image, J, FI, FJ);
      } else {
        hipLaunchKernelGGL((n1_kernel<false>), dim3(8, 64, 1), dim3(256), 0,
                           stream, image, J, FI, FJ);
      }
      hipLaunchKernelGGL(n2_kernel, dim3(64, 8, 1), dim3(256), 0, stream,
                         FI, FJ, wsf + 7);
    }
  }

  hipLaunchKernelGGL(final_kernel, dim3(1), dim3(1), 0, stream,
                     wsf, time_diff, out);
}